// Round 8
// baseline (616.706 us; speedup 1.0000x reference)
//
#include <hip/hip_runtime.h>
#include <hip/hip_bf16.h>
#include <hip/hip_cooperative_groups.h>

namespace cg = cooperative_groups;

// H=256, B=512 graphs, N=200000 nodes, 3 steps.
// Primary: ONE cooperative kernel, 256 blocks x 512 threads (2 graphs/block in
// parallel halves). Fallback (if cooperative launch is rejected): R6 multi-kernel.
#define HID 256
#define NG 512

__device__ __forceinline__ float sigmoidf_(float v) { return 1.f / (1.f + __expf(-v)); }

struct SM {
    float As[16][76];
    float Bs[16][76];
    float ql[HID];
    float red[4][HID];
    float mw[4], lw[4];
};

// ---------------------------------------------------------------------------
// 64x64 C-tile at (m0,n0): A[M x Kslice] * B[N x Kslice]^T -> C. 256 threads
// (ltid). __syncthreads() is full-block: callers guarantee both halves call
// with identical trip counts.
__device__ __forceinline__ void gemm_tile(
    const float* __restrict__ A, int lda, const float* __restrict__ B, int ldb,
    float* __restrict__ C, int ldc, int m0, int n0, int kb, int KS,
    SM& sm, int ltid)
{
    const int tx = ltid & 15, ty = ltid >> 4;
    const int r = ltid >> 2, kc = (ltid & 3) << 2;
    float acc[4][4] = {};
    const float* Ap = &A[(size_t)(m0 + r) * lda + kb + kc];
    const float* Bp = &B[(size_t)(n0 + r) * ldb + kb + kc];
    float4 av = *(const float4*)Ap;
    float4 bv = *(const float4*)Bp;
    for (int k0 = 0; k0 < KS; k0 += 16) {
        sm.As[kc + 0][r] = av.x; sm.As[kc + 1][r] = av.y;
        sm.As[kc + 2][r] = av.z; sm.As[kc + 3][r] = av.w;
        sm.Bs[kc + 0][r] = bv.x; sm.Bs[kc + 1][r] = bv.y;
        sm.Bs[kc + 2][r] = bv.z; sm.Bs[kc + 3][r] = bv.w;
        __syncthreads();
        if (k0 + 16 < KS) {
            av = *(const float4*)(Ap + k0 + 16);
            bv = *(const float4*)(Bp + k0 + 16);
        }
        #pragma unroll
        for (int kk = 0; kk < 16; ++kk) {
            float4 a  = *(const float4*)&sm.As[kk][ty << 2];
            float4 b4 = *(const float4*)&sm.Bs[kk][tx << 2];
            acc[0][0] += a.x * b4.x; acc[0][1] += a.x * b4.y; acc[0][2] += a.x * b4.z; acc[0][3] += a.x * b4.w;
            acc[1][0] += a.y * b4.x; acc[1][1] += a.y * b4.y; acc[1][2] += a.y * b4.z; acc[1][3] += a.y * b4.w;
            acc[2][0] += a.z * b4.x; acc[2][1] += a.z * b4.y; acc[2][2] += a.z * b4.z; acc[2][3] += a.z * b4.w;
            acc[3][0] += a.w * b4.x; acc[3][1] += a.w * b4.y; acc[3][2] += a.w * b4.z; acc[3][3] += a.w * b4.w;
        }
        __syncthreads();
    }
    #pragma unroll
    for (int i = 0; i < 4; ++i) {
        float4 o = make_float4(acc[i][0], acc[i][1], acc[i][2], acc[i][3]);
        *(float4*)&C[(size_t)(m0 + ty * 4 + i) * ldc + n0 + (tx << 2)] = o;
    }
}

// ---------------------------------------------------------------------------
// LSTM + attention + readout for graph g; 256 threads (one half). Exactly TWO
// unconditional __syncthreads so both halves stay barrier-aligned.
__device__ __forceinline__ void attn_graph_half(
    const float* __restrict__ x, const int* __restrict__ starts,
    const float* __restrict__ gp, const float* __restrict__ bcat,
    float* __restrict__ qs, float& cstate, int g, int ltid, int step0, SM& sm)
{
    float ig, fg, gg, og;
    ig = bcat[ltid]; fg = bcat[256 + ltid]; gg = bcat[512 + ltid]; og = bcat[768 + ltid];
    if (!step0) {
        const float* a0 = gp + (size_t)g * 1024;
        #pragma unroll
        for (int z = 0; z < 4; ++z) {
            const float* az = a0 + (size_t)z * 512 * 1024;
            ig += az[ltid]; fg += az[256 + ltid]; gg += az[512 + ltid]; og += az[768 + ltid];
        }
    }
    float cp = step0 ? 0.f : cstate;
    float cn = sigmoidf_(fg) * cp + sigmoidf_(ig) * tanhf(gg);
    float h  = sigmoidf_(og) * tanhf(cn);
    cstate = cn;
    qs[(size_t)g * 512 + ltid] = h;      // q_star[:, :256] = hs
    sm.ql[ltid] = h;

    const int s0 = starts[g];
    const int nn = starts[g + 1] - s0;
    __syncthreads();                     // barrier #1 (unconditional)

    const int w = ltid >> 6, lane = ltid & 63;
    const float NEG = -3.402823466e38f;
    float m_run = NEG, l_run = 0.f;
    float4 racc = make_float4(0.f, 0.f, 0.f, 0.f);

    if (nn > 0) {
        const float4 qv = *(const float4*)&sm.ql[lane * 4];
        const float* xg = x + (size_t)s0 * HID + lane * 4;
        const int lastrow = nn - 1;
        float4 y0, y1, y2, y3, z0, z1, z2, z3;

        int row0 = 4 * w;
        if (row0 < nn) {
            int r1 = row0 + 1 > lastrow ? lastrow : row0 + 1;
            int r2 = row0 + 2 > lastrow ? lastrow : row0 + 2;
            int r3 = row0 + 3 > lastrow ? lastrow : row0 + 3;
            y0 = *(const float4*)(xg + (size_t)row0 * HID);
            y1 = *(const float4*)(xg + (size_t)r1 * HID);
            y2 = *(const float4*)(xg + (size_t)r2 * HID);
            y3 = *(const float4*)(xg + (size_t)r3 * HID);
        }
        for (; row0 < nn; row0 += 16) {
            const int nr = row0 + 16;
            if (nr < nn) {
                int r1 = nr + 1 > lastrow ? lastrow : nr + 1;
                int r2 = nr + 2 > lastrow ? lastrow : nr + 2;
                int r3 = nr + 3 > lastrow ? lastrow : nr + 3;
                z0 = *(const float4*)(xg + (size_t)nr * HID);
                z1 = *(const float4*)(xg + (size_t)r1 * HID);
                z2 = *(const float4*)(xg + (size_t)r2 * HID);
                z3 = *(const float4*)(xg + (size_t)r3 * HID);
            }
            float d0 = y0.x * qv.x + y0.y * qv.y + y0.z * qv.z + y0.w * qv.w;
            float d1 = y1.x * qv.x + y1.y * qv.y + y1.z * qv.z + y1.w * qv.w;
            float d2 = y2.x * qv.x + y2.y * qv.y + y2.z * qv.z + y2.w * qv.w;
            float d3 = y3.x * qv.x + y3.y * qv.y + y3.z * qv.z + y3.w * qv.w;
            #pragma unroll
            for (int off = 1; off < 64; off <<= 1) {
                d0 += __shfl_xor(d0, off);
                d1 += __shfl_xor(d1, off);
                d2 += __shfl_xor(d2, off);
                d3 += __shfl_xor(d3, off);
            }
            const float e0 = d0;
            const float e1 = (row0 + 1 < nn) ? d1 : NEG;
            const float e2 = (row0 + 2 < nn) ? d2 : NEG;
            const float e3 = (row0 + 3 < nn) ? d3 : NEG;
            const float em = fmaxf(fmaxf(e0, e1), fmaxf(e2, e3));
            if (em > m_run) {            // wave-uniform
                const float alpha = __expf(m_run - em);
                const float p0 = __expf(e0 - em);
                const float p1 = __expf(e1 - em);
                const float p2 = __expf(e2 - em);
                const float p3 = __expf(e3 - em);
                l_run = l_run * alpha + (p0 + p1) + (p2 + p3);
                racc.x = racc.x * alpha + p0 * y0.x + p1 * y1.x + p2 * y2.x + p3 * y3.x;
                racc.y = racc.y * alpha + p0 * y0.y + p1 * y1.y + p2 * y2.y + p3 * y3.y;
                racc.z = racc.z * alpha + p0 * y0.z + p1 * y1.z + p2 * y2.z + p3 * y3.z;
                racc.w = racc.w * alpha + p0 * y0.w + p1 * y1.w + p2 * y2.w + p3 * y3.w;
                m_run = em;
            } else {
                const float p0 = __expf(e0 - m_run);
                const float p1 = __expf(e1 - m_run);
                const float p2 = __expf(e2 - m_run);
                const float p3 = __expf(e3 - m_run);
                l_run += (p0 + p1) + (p2 + p3);
                racc.x += p0 * y0.x + p1 * y1.x + p2 * y2.x + p3 * y3.x;
                racc.y += p0 * y0.y + p1 * y1.y + p2 * y2.y + p3 * y3.y;
                racc.z += p0 * y0.z + p1 * y1.z + p2 * y2.z + p3 * y3.z;
                racc.w += p0 * y0.w + p1 * y1.w + p2 * y2.w + p3 * y3.w;
            }
            y0 = z0; y1 = z1; y2 = z2; y3 = z3;
        }
    }
    *(float4*)&sm.red[w][lane * 4] = racc;
    if (lane == 0) { sm.mw[w] = m_run; sm.lw[w] = l_run; }
    __syncthreads();                     // barrier #2 (unconditional)

    float rout = 0.f;
    if (nn > 0) {
        const float M = fmaxf(fmaxf(sm.mw[0], sm.mw[1]), fmaxf(sm.mw[2], sm.mw[3]));
        const float f0 = __expf(sm.mw[0] - M), f1 = __expf(sm.mw[1] - M);
        const float f2 = __expf(sm.mw[2] - M), f3 = __expf(sm.mw[3] - M);
        const float L = sm.lw[0] * f0 + sm.lw[1] * f1 + sm.lw[2] * f2 + sm.lw[3] * f3;
        rout = (sm.red[0][ltid] * f0 + sm.red[1][ltid] * f1
              + sm.red[2][ltid] * f2 + sm.red[3][ltid] * f3) / L;
    }
    qs[(size_t)g * 512 + HID + ltid] = rout;
}

// ---------------------------------------------------------------------------
__global__ __launch_bounds__(512, 2) void fused_kernel(
    const float* __restrict__ x, const int* __restrict__ batch,
    const float* __restrict__ W_ih, const float* __restrict__ W_hh,
    const float* __restrict__ b_ih, const float* __restrict__ b_hh,
    const float* __restrict__ W_out, const float* __restrict__ b_out,
    float* __restrict__ out, int n, char* __restrict__ ws)
{
    __shared__ SM sm2[2];
    float* qs     = (float*)(ws);                 // [512][512]
    float* gp     = (float*)(ws + 0x100000);      // [4][512][1024]
    float* Wcat   = (float*)(ws + 0x900000);      // [1024][512]
    float* bcat   = (float*)(ws + 0xB00000);      // [1024]
    int*   starts = (int*)  (ws + 0xB01000);      // [513]
    float* op     = (float*)(ws + 0xB10000);      // [16][512][256]

    cg::grid_group grid = cg::this_grid();
    const int b = blockIdx.x, tid = threadIdx.x;
    const int hf = tid >> 8, ltid = tid & 255;
    const int htask = b * 2 + hf;                 // 0..511
    const int gtid = b * 512 + tid;               // 0..131071
    SM& sm = sm2[hf];

    // ---- Phase A: Wcat / bcat / starts
    {
        int o = gtid * 4;
        int k = o & 511, row = o >> 9;
        float4 v = *(const float4*)&W_ih[o];
        if (k < 256) {
            float4 u = *(const float4*)&W_hh[row * 256 + k];
            v.x += u.x; v.y += u.y; v.z += u.z; v.w += u.w;
        }
        *(float4*)&Wcat[o] = v;
    }
    if (gtid < 1024) bcat[gtid] = b_ih[gtid] + b_hh[gtid];
    if (gtid <= NG) {
        if (gtid == NG) starts[NG] = n;
        else {
            int lo = 0, hi = n;
            while (lo < hi) {
                int mid = (lo + hi) >> 1;
                if (batch[mid] < gtid) lo = mid + 1; else hi = mid;
            }
            starts[gtid] = lo;
        }
    }
    grid.sync();

    float cstate = 0.f;                           // LSTM c for graph htask
    for (int step = 0; step < 3; ++step) {
        if (step > 0) {
            // gates split-K4: 512 half-tasks, KS=128 (equal barriers both halves)
            int bz = htask >> 7, rem = htask & 127;
            gemm_tile(qs, 512, Wcat, 512, gp + (size_t)bz * 512 * 1024, 1024,
                      (rem >> 4) * 64, (rem & 15) * 64, bz * 128, 128, sm, ltid);
            grid.sync();
        }
        attn_graph_half(x, starts, gp, bcat, qs, cstate, htask, ltid, step == 0, sm);
        grid.sync();
    }

    // ---- out = qs @ W_out^T (+bias after reduce): split-K16, 512 half-tasks
    {
        int bz = htask >> 5, rem = htask & 31;
        gemm_tile(qs, 512, W_out, 512, op + (size_t)bz * 512 * 256, 256,
                  (rem >> 2) * 64, (rem & 3) * 64, bz * 32, 32, sm, ltid);
    }
    grid.sync();
    {
        float v = b_out[gtid & 255];
        #pragma unroll
        for (int z = 0; z < 16; ++z) v += op[(size_t)z * 131072 + gtid];
        out[gtid] = v;
    }
}

// ===========================================================================
// Fallback path (R6 multi-kernel, proven): used only if cooperative launch
// is rejected by the runtime.
// ===========================================================================
__global__ __launch_bounds__(256) void prep_kernel(
    const float* __restrict__ W_ih, const float* __restrict__ W_hh,
    const float* __restrict__ b_ih, const float* __restrict__ b_hh,
    const int* __restrict__ batch, int n,
    float* __restrict__ Wcat, float* __restrict__ bcat, int* __restrict__ starts)
{
    int b = blockIdx.x, tid = threadIdx.x;
    if (b < 512) {
        int o = (b * 256 + tid) * 4;
        int k = o & 511, row = o >> 9;
        float4 v = *(const float4*)&W_ih[o];
        if (k < 256) {
            float4 u = *(const float4*)&W_hh[row * 256 + k];
            v.x += u.x; v.y += u.y; v.z += u.z; v.w += u.w;
        }
        *(float4*)&Wcat[o] = v;
    } else if (b < 516) {
        int i = (b - 512) * 256 + tid;
        bcat[i] = b_ih[i] + b_hh[i];
    } else {
        int g = (b - 516) * 256 + tid;
        if (g > NG) return;
        if (g == NG) { starts[NG] = n; return; }
        int lo = 0, hi = n;
        while (lo < hi) {
            int mid = (lo + hi) >> 1;
            if (batch[mid] < g) lo = mid + 1; else hi = mid;
        }
        starts[g] = lo;
    }
}

__global__ __launch_bounds__(256) void attn_kernel(
    const float* __restrict__ x, const int* __restrict__ starts,
    const float* __restrict__ gp, const float* __restrict__ bcat,
    float* __restrict__ cs, float* __restrict__ qs, int step0)
{
    __shared__ SM sm;
    const int g = blockIdx.x, tid = threadIdx.x;
    float dummy_c = 0.f;
    float cprev = step0 ? 0.f : cs[g * HID + tid];
    (void)dummy_c;
    // LSTM identical to fused but cstate via global cs
    float ig = bcat[tid], fg = bcat[256 + tid], gg = bcat[512 + tid], og = bcat[768 + tid];
    if (!step0) {
        const float* a0 = gp + (size_t)g * 1024;
        #pragma unroll
        for (int z = 0; z < 4; ++z) {
            const float* az = a0 + (size_t)z * 512 * 1024;
            ig += az[tid]; fg += az[256 + tid]; gg += az[512 + tid]; og += az[768 + tid];
        }
    }
    float cn = sigmoidf_(fg) * cprev + sigmoidf_(ig) * tanhf(gg);
    float h  = sigmoidf_(og) * tanhf(cn);
    cs[g * HID + tid] = cn;
    float cst = cn;
    // reuse the half routine minus LSTM: inline remainder
    qs[(size_t)g * 512 + tid] = h;
    sm.ql[tid] = h;
    const int s0 = starts[g];
    const int nn = starts[g + 1] - s0;
    __syncthreads();
    const int w = tid >> 6, lane = tid & 63;
    const float NEG = -3.402823466e38f;
    float m_run = NEG, l_run = 0.f;
    float4 racc = make_float4(0.f, 0.f, 0.f, 0.f);
    if (nn > 0) {
        const float4 qv = *(const float4*)&sm.ql[lane * 4];
        const float* xg = x + (size_t)s0 * HID + lane * 4;
        const int lastrow = nn - 1;
        float4 y0, y1, y2, y3, z0, z1, z2, z3;
        int row0 = 4 * w;
        if (row0 < nn) {
            int r1 = row0 + 1 > lastrow ? lastrow : row0 + 1;
            int r2 = row0 + 2 > lastrow ? lastrow : row0 + 2;
            int r3 = row0 + 3 > lastrow ? lastrow : row0 + 3;
            y0 = *(const float4*)(xg + (size_t)row0 * HID);
            y1 = *(const float4*)(xg + (size_t)r1 * HID);
            y2 = *(const float4*)(xg + (size_t)r2 * HID);
            y3 = *(const float4*)(xg + (size_t)r3 * HID);
        }
        for (; row0 < nn; row0 += 16) {
            const int nr = row0 + 16;
            if (nr < nn) {
                int r1 = nr + 1 > lastrow ? lastrow : nr + 1;
                int r2 = nr + 2 > lastrow ? lastrow : nr + 2;
                int r3 = nr + 3 > lastrow ? lastrow : nr + 3;
                z0 = *(const float4*)(xg + (size_t)nr * HID);
                z1 = *(const float4*)(xg + (size_t)r1 * HID);
                z2 = *(const float4*)(xg + (size_t)r2 * HID);
                z3 = *(const float4*)(xg + (size_t)r3 * HID);
            }
            float d0 = y0.x * qv.x + y0.y * qv.y + y0.z * qv.z + y0.w * qv.w;
            float d1 = y1.x * qv.x + y1.y * qv.y + y1.z * qv.z + y1.w * qv.w;
            float d2 = y2.x * qv.x + y2.y * qv.y + y2.z * qv.z + y2.w * qv.w;
            float d3 = y3.x * qv.x + y3.y * qv.y + y3.z * qv.z + y3.w * qv.w;
            #pragma unroll
            for (int off = 1; off < 64; off <<= 1) {
                d0 += __shfl_xor(d0, off);
                d1 += __shfl_xor(d1, off);
                d2 += __shfl_xor(d2, off);
                d3 += __shfl_xor(d3, off);
            }
            const float e0 = d0;
            const float e1 = (row0 + 1 < nn) ? d1 : NEG;
            const float e2 = (row0 + 2 < nn) ? d2 : NEG;
            const float e3 = (row0 + 3 < nn) ? d3 : NEG;
            const float em = fmaxf(fmaxf(e0, e1), fmaxf(e2, e3));
            if (em > m_run) {
                const float alpha = __expf(m_run - em);
                const float p0 = __expf(e0 - em), p1 = __expf(e1 - em);
                const float p2 = __expf(e2 - em), p3 = __expf(e3 - em);
                l_run = l_run * alpha + (p0 + p1) + (p2 + p3);
                racc.x = racc.x * alpha + p0 * y0.x + p1 * y1.x + p2 * y2.x + p3 * y3.x;
                racc.y = racc.y * alpha + p0 * y0.y + p1 * y1.y + p2 * y2.y + p3 * y3.y;
                racc.z = racc.z * alpha + p0 * y0.z + p1 * y1.z + p2 * y2.z + p3 * y3.z;
                racc.w = racc.w * alpha + p0 * y0.w + p1 * y1.w + p2 * y2.w + p3 * y3.w;
                m_run = em;
            } else {
                const float p0 = __expf(e0 - m_run), p1 = __expf(e1 - m_run);
                const float p2 = __expf(e2 - m_run), p3 = __expf(e3 - m_run);
                l_run += (p0 + p1) + (p2 + p3);
                racc.x += p0 * y0.x + p1 * y1.x + p2 * y2.x + p3 * y3.x;
                racc.y += p0 * y0.y + p1 * y1.y + p2 * y2.y + p3 * y3.y;
                racc.z += p0 * y0.z + p1 * y1.z + p2 * y2.z + p3 * y3.z;
                racc.w += p0 * y0.w + p1 * y1.w + p2 * y2.w + p3 * y3.w;
            }
            y0 = z0; y1 = z1; y2 = z2; y3 = z3;
        }
    }
    (void)cst;
    *(float4*)&sm.red[w][lane * 4] = racc;
    if (lane == 0) { sm.mw[w] = m_run; sm.lw[w] = l_run; }
    __syncthreads();
    float rout = 0.f;
    if (nn > 0) {
        const float M = fmaxf(fmaxf(sm.mw[0], sm.mw[1]), fmaxf(sm.mw[2], sm.mw[3]));
        const float f0 = __expf(sm.mw[0] - M), f1 = __expf(sm.mw[1] - M);
        const float f2 = __expf(sm.mw[2] - M), f3 = __expf(sm.mw[3] - M);
        const float L = sm.lw[0] * f0 + sm.lw[1] * f1 + sm.lw[2] * f2 + sm.lw[3] * f3;
        rout = (sm.red[0][tid] * f0 + sm.red[1][tid] * f1
              + sm.red[2][tid] * f2 + sm.red[3][tid] * f3) / L;
    }
    qs[(size_t)g * 512 + HID + tid] = rout;
}

__global__ __launch_bounds__(256) void gemm_splitk(
    const float* __restrict__ A, int lda,
    const float* __restrict__ B, int ldb,
    float* __restrict__ Cp, int ldc, int KS, size_t slice_stride)
{
    __shared__ SM sm;
    gemm_tile(A, lda, B, ldb, Cp + blockIdx.z * slice_stride, ldc,
              blockIdx.y * 64, blockIdx.x * 64, blockIdx.z * KS, KS,
              sm, threadIdx.x);
}

__global__ __launch_bounds__(256) void finalize_out(
    const float* __restrict__ op, const float* __restrict__ b_out,
    float* __restrict__ out)
{
    int i = blockIdx.x * 256 + threadIdx.x;
    float v = b_out[i & 255];
    #pragma unroll
    for (int z = 0; z < 4; ++z) v += op[(size_t)z * 131072 + i];
    out[i] = v;
}

// ---------------------------------------------------------------------------
extern "C" void kernel_launch(void* const* d_in, const int* in_sizes, int n_in,
                              void* d_out, int out_size, void* d_ws, size_t ws_size,
                              hipStream_t stream)
{
    const float* x     = (const float*)d_in[0];
    const int*   batch = (const int*)d_in[1];
    const float* W_ih  = (const float*)d_in[2];
    const float* W_hh  = (const float*)d_in[3];
    const float* b_ih  = (const float*)d_in[4];
    const float* b_hh  = (const float*)d_in[5];
    const float* W_out = (const float*)d_in[6];
    const float* b_out = (const float*)d_in[7];
    float* out = (float*)d_out;
    int n = in_sizes[1];
    char* ws = (char*)d_ws;
    (void)n_in; (void)out_size; (void)ws_size;

    void* args[] = { (void*)&x, (void*)&batch, (void*)&W_ih, (void*)&W_hh,
                     (void*)&b_ih, (void*)&b_hh, (void*)&W_out, (void*)&b_out,
                     (void*)&out, (void*)&n, (void*)&ws };
    hipError_t rc = hipLaunchCooperativeKernel((const void*)fused_kernel,
                                               dim3(256), dim3(512), args, 0, stream);
    if (rc == hipSuccess) return;

    // -------- fallback: R6-style multi-kernel (shares fused ws layout) -----
    float* qs     = (float*)(ws);
    float* gp     = (float*)(ws + 0x100000);      // [4][512][1024]
    float* Wcat   = (float*)(ws + 0x900000);
    float* bcat   = (float*)(ws + 0xB00000);
    int*   starts = (int*)  (ws + 0xB01000);
    float* op     = (float*)(ws + 0xB10000);      // [4][512][256] (K4 here)
    float* cs     = (float*)(ws + 0xD10000);      // [512][256]

    prep_kernel<<<519, 256, 0, stream>>>(W_ih, W_hh, b_ih, b_hh, batch, n,
                                         Wcat, bcat, starts);
    for (int step = 0; step < 3; ++step) {
        if (step > 0) {
            gemm_splitk<<<dim3(16, 8, 4), 256, 0, stream>>>(
                qs, 512, Wcat, 512, gp, 1024, 128, (size_t)512 * 1024);
        }
        attn_kernel<<<NG, 256, 0, stream>>>(x, starts, gp, bcat, cs, qs, step == 0);
    }
    gemm_splitk<<<dim3(4, 8, 4), 256, 0, stream>>>(
        qs, 512, W_out, 512, op, 256, 128, (size_t)512 * 256);
    finalize_out<<<512, 256, 0, stream>>>(op, b_out, out);
}